// Round 6
// baseline (524.491 us; speedup 1.0000x reference)
//
#include <hip/hip_runtime.h>

// DynamicRouting: votes [B=32, NIN=2048, NOUT=64, ATOMS=16] fp32, 3 iters.
// R10 = R9 resubmission + hardening (3rd infra-level failure was on a
// DIFFERENT structure each time; R9's audit found no kernel fault, and the
// passing rounds showed degraded infra: pytest 173s, acquire 167s).
// Design (unchanged from R9): route passes stage votes rows into LDS via
// async global_load_lds (double-buffered 4KB row per wave) instead of
// register float4 loads.
// Theory: route passes ran at ~2-3 TB/s because in-flight bytes were
// VGPR-capped (RBATCH=2 -> 8x16B/lane in flight). global_load_lds decouples
// in-flight bytes from VGPRs: 4x1KB loads per row stay in flight under
// vmcnt(4) while the previous row computes from LDS (conflict-free
// ds_read_b128, lanes at consecutive 16B).
// Hardening vs R9: sched_barrier(0) after each inline-asm waitcnt (guide
// rule #18) so no dependent op is compiler-hoisted above the wait.
// vmcnt(4) safety: row r's 4 loads are the OLDEST outstanding VMEM ops at
// the wait; "<=4 outstanding" guarantees row r landed.
// LDS: 4 waves x 2 bufs x 4KB = 32 KiB, overlaid (post-barrier) with the
// 16 KiB block-reduce buffer -> 4 blocks/CU retained.

#define NB 32
#define NIN 2048
#define NOUT 64
#define ATOMS 16
#define EPSF 1e-9f

#define ROWS_PER_WAVE 8
#define WAVES_PER_BLOCK 4
#define ROWS_PER_BLOCK (ROWS_PER_WAVE * WAVES_PER_BLOCK) // 32
#define CHUNKS (NIN / ROWS_PER_BLOCK)                    // 64

__device__ __forceinline__ float4 f4add(float4 a, float4 b) {
    return make_float4(a.x + b.x, a.y + b.y, a.z + b.z, a.w + b.w);
}
__device__ __forceinline__ float4 f4fma(float c, float4 v, float4 a) {
    return make_float4(fmaf(c, v.x, a.x), fmaf(c, v.y, a.y),
                       fmaf(c, v.z, a.z), fmaf(c, v.w, a.w));
}
__device__ __forceinline__ float f4dot(float4 a, float4 b) {
    float d = a.x * b.x;
    d = fmaf(a.y, b.y, d); d = fmaf(a.z, b.z, d); d = fmaf(a.w, b.w, d);
    return d;
}

// async 16B/lane global->LDS copy. LDS dest is wave-uniform; HW adds
// lane*16. Global src is per-lane.
__device__ __forceinline__ void gload_lds16(const void* g, void* l) {
    __builtin_amdgcn_global_load_lds(
        (const __attribute__((address_space(1))) void*)g,
        (__attribute__((address_space(3))) void*)l, 16, 0, 0);
}

// stage row r of this wave's window into buf: 4 x 1KB async copies
__device__ __forceinline__ void stage_row(
    const char* vbase_lane, float4* wstage, int r, int buf)
{
#pragma unroll
    for (int q = 0; q < 4; ++q)
        gload_lds16(vbase_lane + (size_t)r * 4096 + q * 1024,
                    wstage + buf * 256 + q * 64);
}

__device__ __forceinline__ void wait_vm4() {
    asm volatile("s_waitcnt vmcnt(4)" ::: "memory");
    __builtin_amdgcn_sched_barrier(0);
}
__device__ __forceinline__ void wait_vm0() {
    asm volatile("s_waitcnt vmcnt(0)" ::: "memory");
    __builtin_amdgcn_sched_barrier(0);
}

// ---------------- pass 0: uniform c = 1/64 --------------------------------
__global__ __launch_bounds__(256, 4) void route0_lds(
    const float4* __restrict__ votes4,
    float4* __restrict__ partials4)
{
    __shared__ float4 stage4[WAVES_PER_BLOCK * 2 * 256]; // 32 KiB
    const int b     = blockIdx.x / CHUNKS;
    const int chunk = blockIdx.x % CHUNKS;
    const int wave  = threadIdx.x >> 6;
    const int lane  = threadIdx.x & 63;
    const int in0   = chunk * ROWS_PER_BLOCK + wave * ROWS_PER_WAVE;

    const char* vbase = (const char*)(votes4 + (size_t)(b * NIN + in0) * 256)
                        + lane * 16;
    float4* wstage = stage4 + wave * 512;

    stage_row(vbase, wstage, 0, 0); // prologue

    float4 acc[4];
#pragma unroll
    for (int j = 0; j < 4; ++j) acc[j] = make_float4(0.f, 0.f, 0.f, 0.f);

    for (int r = 0; r < ROWS_PER_WAVE; ++r) {
        if (r + 1 < ROWS_PER_WAVE) {
            stage_row(vbase, wstage, r + 1, (r + 1) & 1);
            wait_vm4();
        } else {
            wait_vm0();
        }
        const float4* vb = wstage + (r & 1) * 256 + lane;
#pragma unroll
        for (int j = 0; j < 4; ++j)
            acc[j] = f4add(acc[j], vb[j * 64]); // ds_read_b128, conflict-free
    }
#pragma unroll
    for (int j = 0; j < 4; ++j) {
        acc[j].x *= (1.f / 64.f); acc[j].y *= (1.f / 64.f);
        acc[j].z *= (1.f / 64.f); acc[j].w *= (1.f / 64.f);
    }

    __syncthreads(); // all staging reads done; overlay reduce buffer
#pragma unroll
    for (int j = 0; j < 4; ++j)
        stage4[wave * 256 + j * 64 + lane] = acc[j];
    __syncthreads();

    float4* pblock4 = partials4 + ((size_t)(b * CHUNKS + chunk) << 8);
    {
        int idx = threadIdx.x;
        float4 a = stage4[idx], b2 = stage4[256 + idx],
               c = stage4[512 + idx], d = stage4[768 + idx];
        float4 t;
        t.x = (a.x + b2.x) + (c.x + d.x);
        t.y = (a.y + b2.y) + (c.y + d.y);
        t.z = (a.z + b2.z) + (c.z + d.z);
        t.w = (a.w + b2.w) + (c.w + d.w);
        pblock4[idx] = t;
    }
}

// ---------------- passes 1-2: softmax(c)-weighted pool --------------------
// lane holds atoms [4q..4q+3] (q=lane&3) of out o_j = j*16 + (lane>>2).
__global__ __launch_bounds__(256, 4) void route_pose_lds(
    const float4* __restrict__ votes4,
    const float4* __restrict__ pose_accum4,
    float4* __restrict__ partials4)
{
    __shared__ float4 stage4[WAVES_PER_BLOCK * 2 * 256]; // 32 KiB
    const int b     = blockIdx.x / CHUNKS;
    const int chunk = blockIdx.x % CHUNKS;
    const int wave  = threadIdx.x >> 6;
    const int lane  = threadIdx.x & 63;
    const int in0   = chunk * ROWS_PER_BLOCK + wave * ROWS_PER_WAVE;

    float4 pse[4];
#pragma unroll
    for (int j = 0; j < 4; ++j)
        pse[j] = pose_accum4[(b * NOUT + j * 16 + (lane >> 2)) * 4 + (lane & 3)];

    const char* vbase = (const char*)(votes4 + (size_t)(b * NIN + in0) * 256)
                        + lane * 16;
    float4* wstage = stage4 + wave * 512;

    stage_row(vbase, wstage, 0, 0); // prologue

    float4 acc[4];
#pragma unroll
    for (int j = 0; j < 4; ++j) acc[j] = make_float4(0.f, 0.f, 0.f, 0.f);

    for (int r = 0; r < ROWS_PER_WAVE; ++r) {
        if (r + 1 < ROWS_PER_WAVE) {
            stage_row(vbase, wstage, r + 1, (r + 1) & 1);
            wait_vm4();
        } else {
            wait_vm0();
        }
        const float4* vb = wstage + (r & 1) * 256 + lane;

        float4 v[4];
        float lg[4];
#pragma unroll
        for (int j = 0; j < 4; ++j) {
            v[j] = vb[j * 64];               // ds_read_b128, conflict-free
            lg[j] = f4dot(v[j], pse[j]);
        }
        // quad-reduce (atoms split across lanes q=0..3)
#pragma unroll
        for (int mask = 1; mask <= 2; mask <<= 1)
#pragma unroll
            for (int j = 0; j < 4; ++j)
                lg[j] += __shfl_xor(lg[j], mask, 64);

        float e[4], s = 0.f;
#pragma unroll
        for (int j = 0; j < 4; ++j) { e[j] = __expf(lg[j]); s += e[j]; }
        // sum over the 16 quad-groups -> full softmax denom over 64 outs
#pragma unroll
        for (int mask = 4; mask <= 32; mask <<= 1)
            s += __shfl_xor(s, mask, 64);

        float inv = __frcp_rn(s);
#pragma unroll
        for (int j = 0; j < 4; ++j)
            acc[j] = f4fma(e[j] * inv, v[j], acc[j]);
    }

    __syncthreads(); // all staging reads done; overlay reduce buffer
#pragma unroll
    for (int j = 0; j < 4; ++j)
        stage4[wave * 256 + j * 64 + lane] = acc[j];
    __syncthreads();

    float4* pblock4 = partials4 + ((size_t)(b * CHUNKS + chunk) << 8);
    {
        int idx = threadIdx.x;
        float4 a = stage4[idx], b2 = stage4[256 + idx],
               c = stage4[512 + idx], d = stage4[768 + idx];
        float4 t;
        t.x = (a.x + b2.x) + (c.x + d.x);
        t.y = (a.y + b2.y) + (c.y + d.y);
        t.z = (a.z + b2.z) + (c.z + d.z);
        t.w = (a.w + b2.w) + (c.w + d.w);
        pblock4[idx] = t;
    }
}

// ---- reduce 64 chunk-partials, squash (exact R0 kernel) ------------------
__global__ __launch_bounds__(256) void squash_reduce(
    const float* __restrict__ partials,
    float* __restrict__ pose_accum,
    float* __restrict__ d_out,
    int mode)
{
    int gid = blockIdx.x * 256 + threadIdx.x;  // < NB*NOUT*ATOMS = 32768
    int b  = gid >> 10;
    int oa = gid & 1023;
    const float* p = partials + ((size_t)b << 16) + oa;
    float s0 = 0.f, s1 = 0.f, s2 = 0.f, s3 = 0.f;
#pragma unroll
    for (int c = 0; c < CHUNKS; c += 4) {
        s0 += p[(c + 0) << 10];
        s1 += p[(c + 1) << 10];
        s2 += p[(c + 2) << 10];
        s3 += p[(c + 3) << 10];
    }
    float s = (s0 + s1) + (s2 + s3);

    float sq = s * s;
#pragma unroll
    for (int mask = 1; mask < ATOMS; mask <<= 1)
        sq += __shfl_xor(sq, mask, 64);
    float norm = sqrtf(sq + EPSF);
    float f = (sq / (1.0f + sq)) / norm;
    float pse = f * s;
    if (mode == 0) {
        pose_accum[gid] = pse;
    } else if (mode == 1) {
        pose_accum[gid] += pse;
    } else {
        d_out[gid] = pse;
        if ((gid & (ATOMS - 1)) == 0) {
            float psq = f * f * sq; // sum over atoms of pose^2
            d_out[NB * NOUT * ATOMS + (gid >> 4)] = sqrtf(psq + EPSF);
        }
    }
}

extern "C" void kernel_launch(void* const* d_in, const int* in_sizes, int n_in,
                              void* d_out, int out_size, void* d_ws, size_t ws_size,
                              hipStream_t stream) {
    const float4* votes4 = (const float4*)d_in[0];
    float* out = (float*)d_out;

    // ws: pose_accum (128 KiB) | partials (8 MiB)
    float* pose_accum = (float*)d_ws;
    float* partials   = pose_accum + NB * NOUT * ATOMS;

    dim3 blk(256);
    dim3 grid_route(NB * CHUNKS);            // 2048 blocks
    dim3 grid_sq(NB * NOUT * ATOMS / 256);   // 128 blocks

    // iter 0: c = 1/64 uniform
    route0_lds<<<grid_route, blk, 0, stream>>>(votes4, (float4*)partials);
    squash_reduce<<<grid_sq, blk, 0, stream>>>(partials, pose_accum, nullptr, 0);

    // iter 1: logits = <votes, pose0>
    route_pose_lds<<<grid_route, blk, 0, stream>>>(
        votes4, (const float4*)pose_accum, (float4*)partials);
    squash_reduce<<<grid_sq, blk, 0, stream>>>(partials, pose_accum, nullptr, 1);

    // iter 2: logits = <votes, pose0+pose1>
    route_pose_lds<<<grid_route, blk, 0, stream>>>(
        votes4, (const float4*)pose_accum, (float4*)partials);
    squash_reduce<<<grid_sq, blk, 0, stream>>>(partials, nullptr, out, 2);
}

// Round 7
// 499.159 us; speedup vs baseline: 1.0507x; 1.0507x over previous
//
#include <hip/hip_runtime.h>

// DynamicRouting: votes [B=32, NIN=2048, NOUT=64, ATOMS=16] fp32, 3 iters.
// R11: back to the EXACT R0 6-dispatch structure (verified twice).
// Evidence so far: R8 (fp16, half bytes) +42us -> NOT byte-bound.
//                  R10 (LDS staging, 4KB/wave in flight) +78us -> pipeline
//                  got SHALLOWER, not deeper.
// => route passes are LATENCY-bound: too few bytes in flight per CU.
// Two changes, both inside the route kernels:
//  (a) occupancy 4 -> 8 blocks/CU (launch_bounds(256,8); grid 2048 = 8/CU
//      exactly; LDS 16KiB x 8 = 128 <= 160KiB; ~160 VGPR < 256 cap).
//      32 waves/CU of TLP.
//  (b) explicit register pipeline, distance 2: three named 2-row buffers
//      (static indexing only), preload batches 0,1, issue batch k+2 before
//      computing batch k -> >=16KB/wave in flight during every compute.
// Aggregate in-flight ~ 2048 waves x 16KB = 32MB; at ~900cy HBM latency
// that supports ~74 TB/s >> HBM -> pass should drop to the BW/L3 floor.

#define NB 32
#define NIN 2048
#define NOUT 64
#define ATOMS 16
#define EPSF 1e-9f

#define ROWS_PER_WAVE 8
#define WAVES_PER_BLOCK 4
#define ROWS_PER_BLOCK (ROWS_PER_WAVE * WAVES_PER_BLOCK) // 32
#define CHUNKS (NIN / ROWS_PER_BLOCK)                    // 64

__device__ __forceinline__ float4 f4add(float4 a, float4 b) {
    return make_float4(a.x + b.x, a.y + b.y, a.z + b.z, a.w + b.w);
}
__device__ __forceinline__ float4 f4fma(float c, float4 v, float4 a) {
    return make_float4(fmaf(c, v.x, a.x), fmaf(c, v.y, a.y),
                       fmaf(c, v.z, a.z), fmaf(c, v.w, a.w));
}
__device__ __forceinline__ float f4dot(float4 a, float4 b) {
    float d = a.x * b.x;
    d = fmaf(a.y, b.y, d); d = fmaf(a.z, b.z, d); d = fmaf(a.w, b.w, d);
    return d;
}

// load one 2-row batch (8 x float4 = 8 x 1KB-contiguous wave instructions)
__device__ __forceinline__ void load_batch(
    const float4* vrow, int k, float4 v[2][4])
{
    const float4* vp = vrow + (size_t)k * 512;
#pragma unroll
    for (int r = 0; r < 2; ++r)
#pragma unroll
        for (int j = 0; j < 4; ++j)
            v[r][j] = vp[r * 256 + j * 64];
}

// softmax(c)-weighted accumulate for one 2-row batch.
// lane holds atoms [4q..4q+3] (q=lane&3) of out o_j = j*16 + (lane>>2).
__device__ __forceinline__ void compute_batch_pose(
    const float4 v[2][4], const float4 pse[4], float4 acc[4])
{
    float lg[2][4];
#pragma unroll
    for (int r = 0; r < 2; ++r)
#pragma unroll
        for (int j = 0; j < 4; ++j)
            lg[r][j] = f4dot(v[r][j], pse[j]);
    // quad-reduce (atoms split across lanes q=0..3)
#pragma unroll
    for (int mask = 1; mask <= 2; mask <<= 1)
#pragma unroll
        for (int r = 0; r < 2; ++r)
#pragma unroll
            for (int j = 0; j < 4; ++j)
                lg[r][j] += __shfl_xor(lg[r][j], mask, 64);

    float e[2][4], s[2];
#pragma unroll
    for (int r = 0; r < 2; ++r) {
        float t = 0.f;
#pragma unroll
        for (int j = 0; j < 4; ++j) { e[r][j] = __expf(lg[r][j]); t += e[r][j]; }
        s[r] = t;
    }
    // sum over the 16 quad-groups -> full softmax denom over 64 outs
#pragma unroll
    for (int mask = 4; mask <= 32; mask <<= 1)
#pragma unroll
        for (int r = 0; r < 2; ++r)
            s[r] += __shfl_xor(s[r], mask, 64);

#pragma unroll
    for (int r = 0; r < 2; ++r) {
        float inv = __frcp_rn(s[r]);
#pragma unroll
        for (int j = 0; j < 4; ++j)
            acc[j] = f4fma(e[r][j] * inv, v[r][j], acc[j]);
    }
}

__device__ __forceinline__ void compute_batch_sum(
    const float4 v[2][4], float4 acc[4])
{
#pragma unroll
    for (int r = 0; r < 2; ++r)
#pragma unroll
        for (int j = 0; j < 4; ++j)
            acc[j] = f4add(acc[j], v[r][j]);
}

// shared block-reduce epilogue: 4 waves -> one 1024-float partial
__device__ __forceinline__ void block_reduce_store(
    float4* red4, float4* partials4, const float4 acc[4],
    int b, int chunk, int wave, int lane, int tid)
{
#pragma unroll
    for (int j = 0; j < 4; ++j)
        red4[wave * 256 + j * 64 + lane] = acc[j];
    __syncthreads();
    float4* pblock4 = partials4 + ((size_t)(b * CHUNKS + chunk) << 8);
    float4 a = red4[tid], b2 = red4[256 + tid],
           c = red4[512 + tid], d = red4[768 + tid];
    float4 t;
    t.x = (a.x + b2.x) + (c.x + d.x);
    t.y = (a.y + b2.y) + (c.y + d.y);
    t.z = (a.z + b2.z) + (c.z + d.z);
    t.w = (a.w + b2.w) + (c.w + d.w);
    pblock4[tid] = t;
}

// ---------------- pass 0: uniform c = 1/64 --------------------------------
__global__ __launch_bounds__(256, 8) void route0_pf(
    const float4* __restrict__ votes4,
    float4* __restrict__ partials4)
{
    __shared__ float4 red4[WAVES_PER_BLOCK * 256]; // 16 KiB
    const int b     = blockIdx.x / CHUNKS;
    const int chunk = blockIdx.x % CHUNKS;
    const int wave  = threadIdx.x >> 6;
    const int lane  = threadIdx.x & 63;
    const int in0   = chunk * ROWS_PER_BLOCK + wave * ROWS_PER_WAVE;
    const float4* vrow = votes4 + (size_t)(b * NIN + in0) * 256 + lane;

    float4 acc[4];
#pragma unroll
    for (int j = 0; j < 4; ++j) acc[j] = make_float4(0.f, 0.f, 0.f, 0.f);

    // distance-2 register pipeline over 4 batches (8 rows)
    float4 b0[2][4], b1[2][4], b2[2][4];
    load_batch(vrow, 0, b0);
    load_batch(vrow, 1, b1);
    load_batch(vrow, 2, b2);
    compute_batch_sum(b0, acc);
    load_batch(vrow, 3, b0);
    compute_batch_sum(b1, acc);
    compute_batch_sum(b2, acc);
    compute_batch_sum(b0, acc);

#pragma unroll
    for (int j = 0; j < 4; ++j) {
        acc[j].x *= (1.f / 64.f); acc[j].y *= (1.f / 64.f);
        acc[j].z *= (1.f / 64.f); acc[j].w *= (1.f / 64.f);
    }
    block_reduce_store(red4, partials4, acc, b, chunk, wave, lane, threadIdx.x);
}

// ---------------- passes 1-2: softmax(c)-weighted pool --------------------
__global__ __launch_bounds__(256, 8) void route_pose_pf(
    const float4* __restrict__ votes4,
    const float4* __restrict__ pose_accum4,
    float4* __restrict__ partials4)
{
    __shared__ float4 red4[WAVES_PER_BLOCK * 256]; // 16 KiB
    const int b     = blockIdx.x / CHUNKS;
    const int chunk = blockIdx.x % CHUNKS;
    const int wave  = threadIdx.x >> 6;
    const int lane  = threadIdx.x & 63;
    const int in0   = chunk * ROWS_PER_BLOCK + wave * ROWS_PER_WAVE;
    const float4* vrow = votes4 + (size_t)(b * NIN + in0) * 256 + lane;

    float4 pse[4];
#pragma unroll
    for (int j = 0; j < 4; ++j)
        pse[j] = pose_accum4[(b * NOUT + j * 16 + (lane >> 2)) * 4 + (lane & 3)];

    float4 acc[4];
#pragma unroll
    for (int j = 0; j < 4; ++j) acc[j] = make_float4(0.f, 0.f, 0.f, 0.f);

    // distance-2 register pipeline over 4 batches (8 rows)
    float4 b0[2][4], b1[2][4], b2[2][4];
    load_batch(vrow, 0, b0);
    load_batch(vrow, 1, b1);
    load_batch(vrow, 2, b2);
    compute_batch_pose(b0, pse, acc);
    load_batch(vrow, 3, b0);
    compute_batch_pose(b1, pse, acc);
    compute_batch_pose(b2, pse, acc);
    compute_batch_pose(b0, pse, acc);

    block_reduce_store(red4, partials4, acc, b, chunk, wave, lane, threadIdx.x);
}

// ---- reduce 64 chunk-partials, squash (exact R0 kernel) ------------------
__global__ __launch_bounds__(256) void squash_reduce(
    const float* __restrict__ partials,
    float* __restrict__ pose_accum,
    float* __restrict__ d_out,
    int mode)
{
    int gid = blockIdx.x * 256 + threadIdx.x;  // < NB*NOUT*ATOMS = 32768
    int b  = gid >> 10;
    int oa = gid & 1023;
    const float* p = partials + ((size_t)b << 16) + oa;
    float s0 = 0.f, s1 = 0.f, s2 = 0.f, s3 = 0.f;
#pragma unroll
    for (int c = 0; c < CHUNKS; c += 4) {
        s0 += p[(c + 0) << 10];
        s1 += p[(c + 1) << 10];
        s2 += p[(c + 2) << 10];
        s3 += p[(c + 3) << 10];
    }
    float s = (s0 + s1) + (s2 + s3);

    float sq = s * s;
#pragma unroll
    for (int mask = 1; mask < ATOMS; mask <<= 1)
        sq += __shfl_xor(sq, mask, 64);
    float norm = sqrtf(sq + EPSF);
    float f = (sq / (1.0f + sq)) / norm;
    float pse = f * s;
    if (mode == 0) {
        pose_accum[gid] = pse;
    } else if (mode == 1) {
        pose_accum[gid] += pse;
    } else {
        d_out[gid] = pse;
        if ((gid & (ATOMS - 1)) == 0) {
            float psq = f * f * sq; // sum over atoms of pose^2
            d_out[NB * NOUT * ATOMS + (gid >> 4)] = sqrtf(psq + EPSF);
        }
    }
}

extern "C" void kernel_launch(void* const* d_in, const int* in_sizes, int n_in,
                              void* d_out, int out_size, void* d_ws, size_t ws_size,
                              hipStream_t stream) {
    const float4* votes4 = (const float4*)d_in[0];
    float* out = (float*)d_out;

    // ws: pose_accum (128 KiB) | partials (8 MiB)
    float* pose_accum = (float*)d_ws;
    float* partials   = pose_accum + NB * NOUT * ATOMS;

    dim3 blk(256);
    dim3 grid_route(NB * CHUNKS);            // 2048 blocks = 8/CU exactly
    dim3 grid_sq(NB * NOUT * ATOMS / 256);   // 128 blocks

    // iter 0: c = 1/64 uniform
    route0_pf<<<grid_route, blk, 0, stream>>>(votes4, (float4*)partials);
    squash_reduce<<<grid_sq, blk, 0, stream>>>(partials, pose_accum, nullptr, 0);

    // iter 1: logits = <votes, pose0>
    route_pose_pf<<<grid_route, blk, 0, stream>>>(
        votes4, (const float4*)pose_accum, (float4*)partials);
    squash_reduce<<<grid_sq, blk, 0, stream>>>(partials, pose_accum, nullptr, 1);

    // iter 2: logits = <votes, pose0+pose1>
    route_pose_pf<<<grid_route, blk, 0, stream>>>(
        votes4, (const float4*)pose_accum, (float4*)partials);
    squash_reduce<<<grid_sq, blk, 0, stream>>>(partials, nullptr, out, 2);
}